// Round 13
// baseline (31.660 us; speedup 1.0000x reference)
//
#include <hip/hip_runtime.h>
#include <hip/hip_bf16.h>

typedef __attribute__((ext_vector_type(8))) short short8;
typedef __attribute__((ext_vector_type(4))) float f32x4;
typedef __attribute__((ext_vector_type(16))) float f32x16;

#define NROWS 65536             // BATCH * N_EDGES
#define EDGE_DIM 64
#define NODE_DIM 32
#define NN 1024                 // NODE_DIM^2

__device__ __forceinline__ short f2bf(float f) {
    unsigned u = __builtin_bit_cast(unsigned, f);
    u += 0x7FFFu + ((u >> 16) & 1u);            // round-to-nearest-even
    return (short)(u >> 16);
}

// R13 = R12's proven fused body at 4 waves/SIMD. 256 blocks x 1024 threads
// (16 waves): wave w = (ihalf = w>>3, eg = w&7) handles 32 edges x 16 i's.
// Per-CU pipe totals identical to R12 (DS 1024 ds_read_b128, same VALU/MFMA)
// but 2x the waves to overlap them. 1024-thread block forces VGPR<=128;
// single-edge-group body ~100 VGPR -> no spill (R10/R11's two-group bodies
// at ~150 would spill — that was their hidden flaw; R8's cap-to-64 spilled
// catastrophically). Each wave packs 8 W-frags (f32 coalesced col loads,
// L2/L3-hot, conflict-free ds_write_b128); ONE barrier; barrier-free i-loop.
// Fragment layout (verified R2..R12): frag = i*4+ks;
// ldsW[(frag*64+l)*8+t] = bf16(W[ks*16 + (l>>5)*8 + t, i*32 + (l&31)]).
__global__ __launch_bounds__(1024) void mp_fused(
    const float* __restrict__ node, const float* __restrict__ edge,
    const float* __restrict__ W, const float* __restrict__ bias,
    float* __restrict__ out) {
    __shared__ __align__(16) short ldsW[65536];   // 128 KB: full packed W

    const int tid   = threadIdx.x;
    const int wid   = tid >> 6;               // 0..15
    const int l     = tid & 63;
    const int e32   = l & 31;                 // lane's edge col (MFMA N)
    const int h     = l >> 5;                 // lane half (k-group / row offset)
    const int eg    = wid & 7;                // 32-edge group
    const int ibase = (wid >> 3) * 16;        // i-half owned by this wave
    const int eb    = blockIdx.x * 256 + eg * 32;
    const int e     = eb + e32;

    // ---- in-block W pack: wave wid packs frags [wid*8, wid*8+8) ----
#pragma unroll
    for (int m = 0; m < 8; ++m) {
        const int frag = wid * 8 + m;         // frag = i*4 + ks
        const int i  = frag >> 2;
        const int ks = frag & 3;
        const float* wp = W + (size_t)(ks * 16 + h * 8) * NN + i * 32 + e32;
        short8 v;
#pragma unroll
        for (int t = 0; t < 8; ++t)
            v[t] = f2bf(wp[(size_t)t * NN]);  // coalesced across lanes per t
        *reinterpret_cast<short8*>(&ldsW[((size_t)frag * 64 + l) * 8]) = v;
    }

    // ---- per-lane inputs (overlap the pack's VMEM stream) ----
    // ef[ks]: k = h*8+t -> edge[e, ks*16 + h*8 + t]
    // nv[q*4+rr]: acc reg r=q*4+rr -> j = q*8 + h*4 + rr
    short8 ef[4];
    float  nv[16];
    const float* erow = edge + (size_t)e * EDGE_DIM;
#pragma unroll
    for (int ks = 0; ks < 4; ++ks) {
        f32x4 a = *reinterpret_cast<const f32x4*>(erow + ks * 16 + h * 8);
        f32x4 b = *reinterpret_cast<const f32x4*>(erow + ks * 16 + h * 8 + 4);
        short8 v;
        v[0] = f2bf(a[0]); v[1] = f2bf(a[1]); v[2] = f2bf(a[2]); v[3] = f2bf(a[3]);
        v[4] = f2bf(b[0]); v[5] = f2bf(b[1]); v[6] = f2bf(b[2]); v[7] = f2bf(b[3]);
        ef[ks] = v;
    }
    const float* nrow = node + (size_t)e * NODE_DIM;
#pragma unroll
    for (int q = 0; q < 4; ++q) {
        f32x4 n = *reinterpret_cast<const f32x4*>(nrow + q * 8 + h * 4);
        nv[q * 4 + 0] = n[0]; nv[q * 4 + 1] = n[1];
        nv[q * 4 + 2] = n[2]; nv[q * 4 + 3] = n[3];
    }

    __syncthreads();                          // the ONLY barrier

    float* orow = out + (size_t)(eb + (l & 31)) * NODE_DIM + ibase;

#pragma unroll 2
    for (int iq = 0; iq < 4; ++iq) {
        f32x4 vq;
#pragma unroll
        for (int r = 0; r < 4; ++r) {
            const int i = ibase + iq * 4 + r;
            const short* wp = &ldsW[(size_t)i * 2048 + l * 8];
            short8 w0 = *reinterpret_cast<const short8*>(wp + 0 * 512);
            short8 w1 = *reinterpret_cast<const short8*>(wp + 1 * 512);
            short8 w2 = *reinterpret_cast<const short8*>(wp + 2 * 512);
            short8 w3 = *reinterpret_cast<const short8*>(wp + 3 * 512);

            // bias as C-init: reg q*4+rr -> row q*8 + h*4 + rr (L1-hot)
            f32x16 acc;
#pragma unroll
            for (int q = 0; q < 4; ++q) {
                f32x4 bq = *reinterpret_cast<const f32x4*>(bias + i * 32 + q * 8 + h * 4);
                acc[q * 4 + 0] = bq[0]; acc[q * 4 + 1] = bq[1];
                acc[q * 4 + 2] = bq[2]; acc[q * 4 + 3] = bq[3];
            }

            acc = __builtin_amdgcn_mfma_f32_32x32x16_bf16(w0, ef[0], acc, 0, 0, 0);
            acc = __builtin_amdgcn_mfma_f32_32x32x16_bf16(w1, ef[1], acc, 0, 0, 0);
            acc = __builtin_amdgcn_mfma_f32_32x32x16_bf16(w2, ef[2], acc, 0, 0, 0);
            acc = __builtin_amdgcn_mfma_f32_32x32x16_bf16(w3, ef[3], acc, 0, 0, 0);

            // relu + matvec, 4 independent partials (chain depth 4)
            float s0 = 0.f, s1 = 0.f, s2 = 0.f, s3 = 0.f;
#pragma unroll
            for (int rr = 0; rr < 4; ++rr) {
                s0 += fmaxf(acc[rr],      0.f) * nv[rr];
                s1 += fmaxf(acc[4 + rr],  0.f) * nv[4 + rr];
                s2 += fmaxf(acc[8 + rr],  0.f) * nv[8 + rr];
                s3 += fmaxf(acc[12 + rr], 0.f) * nv[12 + rr];
            }
            float p = (s0 + s1) + (s2 + s3);
            p += __shfl_xor(p, 32);           // add partner half's 16 j's
            vq[r] = p;
        }
        if (l < 32)
            *reinterpret_cast<f32x4*>(orow + iq * 4) = vq;  // msg[e, ibase+iq*4..]
    }
}

extern "C" void kernel_launch(void* const* d_in, const int* in_sizes, int n_in,
                              void* d_out, int out_size, void* d_ws, size_t ws_size,
                              hipStream_t stream) {
    const float* node = (const float*)d_in[0];  // [16,4096,32] f32
    const float* edge = (const float*)d_in[1];  // [16,4096,64] f32
    const float* W    = (const float*)d_in[2];  // [64,1024] f32
    const float* bias = (const float*)d_in[3];  // [1024] f32
    float* out = (float*)d_out;                 // [16,4096,32] f32

    mp_fused<<<dim3(NROWS / 256), dim3(1024), 0, stream>>>(node, edge, W, bias, out);
}

// Round 14
// 26.481 us; speedup vs baseline: 1.1956x; 1.1956x over previous
//
#include <hip/hip_runtime.h>
#include <hip/hip_bf16.h>

typedef __attribute__((ext_vector_type(8))) short short8;
typedef __attribute__((ext_vector_type(4))) float f32x4;
typedef __attribute__((ext_vector_type(16))) float f32x16;

#define NROWS 65536             // BATCH * N_EDGES
#define EDGE_DIM 64
#define NODE_DIM 32
#define NN 1024                 // NODE_DIM^2

__device__ __forceinline__ short f2bf(float f) {
    unsigned u = __builtin_bit_cast(unsigned, f);
    u += 0x7FFFu + ((u >> 16) & 1u);            // round-to-nearest-even
    return (short)(u >> 16);
}

// R14 = R12's fused kernel with ONLY the wave-split changed: 256 blocks x
// 512 threads (8 waves), wave w = (eg = w&3 -> 64 edges, ihalf = w>>2 ->
// 16 i's). Each W ds_read now feeds TWO mfma column-groups -> per-CU DS
// reads halve vs R12 (512 vs 1024 ds_read_b128), the dominant pipe in the
// cost model (6.4 -> ~3.5 us). All 64 lanes store f32x4 (R12 used half).
// Pack, fragment layout, epilogue, no-VGPR-cap: identical to R12.
// Fragment layout (verified R2..R13): frag = i*4+ks;
// ldsW[(frag*64+l)*8+t] = bf16(W[ks*16 + (l>>5)*8 + t, i*32 + (l&31)]).
__global__ __launch_bounds__(512) void mp_fused(
    const float* __restrict__ node, const float* __restrict__ edge,
    const float* __restrict__ W, const float* __restrict__ bias,
    float* __restrict__ out) {
    __shared__ __align__(16) short ldsW[65536];   // 128 KB: full packed W

    const int tid   = threadIdx.x;
    const int wid   = tid >> 6;               // 0..7
    const int l     = tid & 63;
    const int e32   = l & 31;                 // lane's edge col (MFMA N)
    const int h     = l >> 5;                 // lane half (k-group / row offset)
    const int eg    = wid & 3;                // 64-edge group
    const int ibase = (wid >> 2) * 16;        // i-half owned by this wave
    const int eb    = blockIdx.x * 256 + eg * 64;

    // ---- in-block W pack: wave wid packs frags [wid*16, wid*16+16) ----
#pragma unroll
    for (int m = 0; m < 16; ++m) {
        const int frag = wid * 16 + m;        // frag = i*4 + ks
        const int i  = frag >> 2;
        const int ks = frag & 3;
        const float* wp = W + (size_t)(ks * 16 + h * 8) * NN + i * 32 + e32;
        short8 v;
#pragma unroll
        for (int t = 0; t < 8; ++t)
            v[t] = f2bf(wp[(size_t)t * NN]);  // coalesced across lanes per t
        *reinterpret_cast<short8*>(&ldsW[((size_t)frag * 64 + l) * 8]) = v;
    }

    // ---- per-lane inputs (overlap the pack's VMEM stream) ----
    // ef[g][ks]: k = h*8+t -> edge[eb + g*32 + e32, ks*16 + h*8 + t]
    // nv[g][q*4+rr]: acc reg r=q*4+rr -> j = q*8 + h*4 + rr
    short8 ef[2][4];
    float  nv[2][16];
#pragma unroll
    for (int g = 0; g < 2; ++g) {
        const float* erow = edge + (size_t)(eb + g * 32 + e32) * EDGE_DIM;
#pragma unroll
        for (int ks = 0; ks < 4; ++ks) {
            f32x4 a = *reinterpret_cast<const f32x4*>(erow + ks * 16 + h * 8);
            f32x4 b = *reinterpret_cast<const f32x4*>(erow + ks * 16 + h * 8 + 4);
            short8 v;
            v[0] = f2bf(a[0]); v[1] = f2bf(a[1]); v[2] = f2bf(a[2]); v[3] = f2bf(a[3]);
            v[4] = f2bf(b[0]); v[5] = f2bf(b[1]); v[6] = f2bf(b[2]); v[7] = f2bf(b[3]);
            ef[g][ks] = v;
        }
        const float* nrow = node + (size_t)(eb + g * 32 + e32) * NODE_DIM;
#pragma unroll
        for (int q = 0; q < 4; ++q) {
            f32x4 n = *reinterpret_cast<const f32x4*>(nrow + q * 8 + h * 4);
            nv[g][q * 4 + 0] = n[0]; nv[g][q * 4 + 1] = n[1];
            nv[g][q * 4 + 2] = n[2]; nv[g][q * 4 + 3] = n[3];
        }
    }

    __syncthreads();                          // the ONLY barrier

    // all 64 lanes store: h picks the 32-edge subgroup
    float* orow = out + (size_t)(eb + h * 32 + e32) * NODE_DIM + ibase;

#pragma unroll 2
    for (int iq = 0; iq < 4; ++iq) {
        f32x4 vq;
#pragma unroll
        for (int r = 0; r < 4; ++r) {
            const int i = ibase + iq * 4 + r;
            const short* wp = &ldsW[(size_t)i * 2048 + l * 8];
            short8 w0 = *reinterpret_cast<const short8*>(wp + 0 * 512);
            short8 w1 = *reinterpret_cast<const short8*>(wp + 1 * 512);
            short8 w2 = *reinterpret_cast<const short8*>(wp + 2 * 512);
            short8 w3 = *reinterpret_cast<const short8*>(wp + 3 * 512);

            // bias as C-init (same for both groups): reg q*4+rr -> row q*8+h*4+rr
            f32x16 acc0, acc1;
#pragma unroll
            for (int q = 0; q < 4; ++q) {
                f32x4 bq = *reinterpret_cast<const f32x4*>(bias + i * 32 + q * 8 + h * 4);
                acc0[q * 4 + 0] = bq[0]; acc0[q * 4 + 1] = bq[1];
                acc0[q * 4 + 2] = bq[2]; acc0[q * 4 + 3] = bq[3];
            }
            acc1 = acc0;

            acc0 = __builtin_amdgcn_mfma_f32_32x32x16_bf16(w0, ef[0][0], acc0, 0, 0, 0);
            acc1 = __builtin_amdgcn_mfma_f32_32x32x16_bf16(w0, ef[1][0], acc1, 0, 0, 0);
            acc0 = __builtin_amdgcn_mfma_f32_32x32x16_bf16(w1, ef[0][1], acc0, 0, 0, 0);
            acc1 = __builtin_amdgcn_mfma_f32_32x32x16_bf16(w1, ef[1][1], acc1, 0, 0, 0);
            acc0 = __builtin_amdgcn_mfma_f32_32x32x16_bf16(w2, ef[0][2], acc0, 0, 0, 0);
            acc1 = __builtin_amdgcn_mfma_f32_32x32x16_bf16(w2, ef[1][2], acc1, 0, 0, 0);
            acc0 = __builtin_amdgcn_mfma_f32_32x32x16_bf16(w3, ef[0][3], acc0, 0, 0, 0);
            acc1 = __builtin_amdgcn_mfma_f32_32x32x16_bf16(w3, ef[1][3], acc1, 0, 0, 0);

            // relu + matvec, 4 independent partials per group (chain depth 4)
            float s00 = 0.f, s01 = 0.f, s02 = 0.f, s03 = 0.f;
            float s10 = 0.f, s11 = 0.f, s12 = 0.f, s13 = 0.f;
#pragma unroll
            for (int rr = 0; rr < 4; ++rr) {
                s00 += fmaxf(acc0[rr],      0.f) * nv[0][rr];
                s01 += fmaxf(acc0[4 + rr],  0.f) * nv[0][4 + rr];
                s02 += fmaxf(acc0[8 + rr],  0.f) * nv[0][8 + rr];
                s03 += fmaxf(acc0[12 + rr], 0.f) * nv[0][12 + rr];
                s10 += fmaxf(acc1[rr],      0.f) * nv[1][rr];
                s11 += fmaxf(acc1[4 + rr],  0.f) * nv[1][4 + rr];
                s12 += fmaxf(acc1[8 + rr],  0.f) * nv[1][8 + rr];
                s13 += fmaxf(acc1[12 + rr], 0.f) * nv[1][12 + rr];
            }
            float p0 = (s00 + s01) + (s02 + s03);
            float p1 = (s10 + s11) + (s12 + s13);
            p0 += __shfl_xor(p0, 32);         // full j-sum, valid in all lanes
            p1 += __shfl_xor(p1, 32);
            vq[r] = h ? p1 : p0;              // lane's edge = eb + h*32 + e32
        }
        *reinterpret_cast<f32x4*>(orow + iq * 4) = vq;  // msg[e, ibase+iq*4..]
    }
}

extern "C" void kernel_launch(void* const* d_in, const int* in_sizes, int n_in,
                              void* d_out, int out_size, void* d_ws, size_t ws_size,
                              hipStream_t stream) {
    const float* node = (const float*)d_in[0];  // [16,4096,32] f32
    const float* edge = (const float*)d_in[1];  // [16,4096,64] f32
    const float* W    = (const float*)d_in[2];  // [64,1024] f32
    const float* bias = (const float*)d_in[3];  // [1024] f32
    float* out = (float*)d_out;                 // [16,4096,32] f32

    mp_fused<<<dim3(NROWS / 256), dim3(512), 0, stream>>>(node, edge, W, bias, out);
}